// Round 1
// baseline (275.124 us; speedup 1.0000x reference)
//
#include <hip/hip_runtime.h>

// QuantizedEmbedding: out[r, d] = code[qw[x[r], d]] * absmax[(x[r]*D + d) >> 12]
//
// Structure: 8 rows per block, 256 threads, 4 elems/thread (int4/float4 = 16B/lane).
//   - Row indices loaded up-front (wave-uniform -> s_load), so the 8 row loads are
//     independent and can all be in flight at once (8 x 16B outstanding per lane).
//   - All offset arithmetic in int32: max qw offset = 50304*1024 < 2^31 elements/bytes.
//   - Non-temporal float4 stores: output is write-once, never re-read; avoids
//     evicting gathered qw rows (≈15% of indices are duplicates) from L2/L3.
//   - Note a whole row (1024 elems) lies inside one 4096-elem absmax block
//     (v*1024 .. v*1024+1023), so absmax is one broadcast scalar per row.

constexpr int RPB = 8;   // rows per block

using vi4 = __attribute__((ext_vector_type(4))) int;
using vf4 = __attribute__((ext_vector_type(4))) float;

__global__ __launch_bounds__(256) void qembed_kernel(
    const int* __restrict__ x,          // [n_rows] gathered indices
    const int* __restrict__ qw,         // [V, D] int32 codes 0..255
    const float* __restrict__ absmax,   // [n_blocks] per-4096-block scales
    const float* __restrict__ code,     // [256] codebook
    float* __restrict__ out,            // [n_rows, D]
    int D, int n_rows)
{
    __shared__ float lcode[256];
    lcode[threadIdx.x] = code[threadIdx.x];

    const int r0 = blockIdx.x * RPB;

    // Wave-uniform index loads (compiler emits scalar loads); all 8 known up-front.
    int vidx[RPB];
#pragma unroll
    for (int i = 0; i < RPB; ++i) {
        const int r = r0 + i;
        vidx[i] = (r < n_rows) ? x[r] : 0;
    }
    __syncthreads();

    // D == 1024 in this problem: loop body executes once; kept general.
    for (int d = threadIdx.x * 4; d < D; d += 256 * 4) {
        vi4   q[RPB];
        float am[RPB];
        // Issue all 8 independent 16B loads first (MLP), then consume.
#pragma unroll
        for (int i = 0; i < RPB; ++i) {
            const int base = vidx[i] * D + d;     // fits int32
            am[i] = absmax[base >> 12];
            q[i]  = *reinterpret_cast<const vi4*>(qw + base);
        }
#pragma unroll
        for (int i = 0; i < RPB; ++i) {
            if (r0 + i < n_rows) {
                vf4 o;
                o.x = lcode[q[i].x & 0xFF] * am[i];
                o.y = lcode[q[i].y & 0xFF] * am[i];
                o.z = lcode[q[i].z & 0xFF] * am[i];
                o.w = lcode[q[i].w & 0xFF] * am[i];
                __builtin_nontemporal_store(
                    o, reinterpret_cast<vf4*>(out + (r0 + i) * D + d));
            }
        }
    }
}

extern "C" void kernel_launch(void* const* d_in, const int* in_sizes, int n_in,
                              void* d_out, int out_size, void* d_ws, size_t ws_size,
                              hipStream_t stream) {
    const int*   x      = (const int*)d_in[0];    // [B*S] indices
    const int*   qw     = (const int*)d_in[1];    // [V*D] int32 codes
    const float* absmax = (const float*)d_in[2];  // [n_blocks]
    const float* code   = (const float*)d_in[3];  // [256]
    float*       out    = (float*)d_out;

    const int n_rows = in_sizes[0];               // 16384
    const int D = out_size / n_rows;              // 1024

    const int grid = (n_rows + RPB - 1) / RPB;    // 2048 blocks
    qembed_kernel<<<grid, 256, 0, stream>>>(x, qw, absmax, code, out, D, n_rows);
}